// Round 12
// baseline (308.053 us; speedup 1.0000x reference)
//
#include <hip/hip_runtime.h>

// B=2, S=2048, D=1024, H=16, DK=64. Inputs fp32 dict-order, output fp32.
// Round 12: single 40MB path; fp32-A in-flight convert in proj (no prep_x);
// attn: r10 scalar softmax + halved P-region two-pass PV -> 3 blocks/CU.

typedef __attribute__((ext_vector_type(8))) __bf16 bf16x8;
typedef __attribute__((ext_vector_type(4))) __bf16 bf16x4;
typedef __attribute__((ext_vector_type(8))) float f32x8;
typedef __attribute__((ext_vector_type(4))) float f32x4;

#define MFMA16 __builtin_amdgcn_mfma_f32_16x16x32_bf16

union Bf8 { bf16x8 v; __bf16 e[8]; };

__device__ inline f32x4 zero4() { f32x4 z; z[0]=z[1]=z[2]=z[3]=0.f; return z; }

__device__ inline void load_lds16(const void* g, void* l) {
    __builtin_amdgcn_global_load_lds(
        (const __attribute__((address_space(1))) unsigned int*)g,
        (__attribute__((address_space(3))) unsigned int*)l, 16, 0, 0);
}

// ---------------------------------------------------------------------------
// Weights: transpose + convert. dst[n][k] (bf16) = src[k][n] (fp32).
// grid (32,32,4), block 256.
// ---------------------------------------------------------------------------
__global__ __launch_bounds__(256) void prep_w(
        const float* __restrict__ w0, const float* __restrict__ w1,
        const float* __restrict__ w2, const float* __restrict__ w3,
        __bf16* __restrict__ wt) {
    const int z = blockIdx.z, t = threadIdx.x;
    const float* src = z == 0 ? w0 : z == 1 ? w1 : z == 2 ? w2 : w3;
    __bf16* dst = wt + (size_t)z * 1048576;
    __shared__ float tile[32][33];
    const int tc = t & 31, tr = t >> 5;
    const int r0 = blockIdx.y * 32, c0 = blockIdx.x * 32;
#pragma unroll
    for (int i = 0; i < 4; i++) {
        int r = tr + i * 8;
        tile[r][tc] = src[(size_t)(r0 + r) * 1024 + c0 + tc];
    }
    __syncthreads();
#pragma unroll
    for (int i = 0; i < 4; i++) {
        int r = tr + i * 8;
        dst[(size_t)(c0 + r) * 1024 + r0 + tc] = (__bf16)tile[tc][r];
    }
}

// ---------------------------------------------------------------------------
// FAST GEMM core. B via global_load_lds(16B); A via global_load_lds (bf16)
// or fp32 vector-load + in-flight convert (AF32) into the SAME swizzled
// layout (stride 64, block cb stored at pc = cb ^ (row&7)).
// MODE 0: row-major fp32; 1: Q/K head layout; 2: V^T with LDS-transpose.
// ---------------------------------------------------------------------------
template <int MODE, bool AF32, typename OutT>
__device__ inline void gemm_fast_core(const void* __restrict__ Av,
                                      const __bf16* __restrict__ Bt,
                                      const float* __restrict__ bias,
                                      OutT* __restrict__ out, float scale) {
    __shared__ __bf16 smem[16384];
    __bf16* As = smem;
    __bf16* Bs = smem + 8192;
    const int t = threadIdx.x;
    const int wave = t >> 6, lane = t & 63, lm = lane & 15, quad = lane >> 4;
    const int m0 = blockIdx.y * 128, n0 = blockIdx.x * 128;
    const int wm = (wave >> 1) * 64, wn = (wave & 1) * 64;

    f32x4 acc[4][4];
#pragma unroll
    for (int i = 0; i < 4; i++)
#pragma unroll
        for (int j = 0; j < 4; j++) acc[i][j] = zero4();

    for (int k0 = 0; k0 < 1024; k0 += 64) {
#pragma unroll
        for (int i = 0; i < 4; i++) {
            int s = i * 256 + t;
            int row = s >> 3, cb = (s & 7) ^ (row & 7);
            size_t goff = (size_t)row * 1024 + k0 + cb * 8;
            if (AF32) {
                f32x8 a = *(const f32x8*)&((const float*)Av)[(size_t)m0 * 1024 + goff];
                Bf8 tmp;
#pragma unroll
                for (int j = 0; j < 8; j++) tmp.e[j] = (__bf16)a[j];
                *(bf16x8*)&As[(size_t)s * 8] = tmp.v;
            } else {
                load_lds16(&((const __bf16*)Av)[(size_t)m0 * 1024 + goff],
                           &As[(size_t)(i * 256 + wave * 64) * 8]);
            }
            load_lds16(&Bt[(size_t)n0 * 1024 + goff],
                       &Bs[(size_t)(i * 256 + wave * 64) * 8]);
        }
        __syncthreads();
#pragma unroll
        for (int ks = 0; ks < 2; ks++) {
            bf16x8 af[4], bfr[4];
#pragma unroll
            for (int mt = 0; mt < 4; mt++)
                af[mt] = *(const bf16x8*)&As[(wm + mt * 16 + lm) * 64 +
                                             (((ks * 4 + quad) ^ (lm & 7)) * 8)];
#pragma unroll
            for (int nt = 0; nt < 4; nt++)
                bfr[nt] = *(const bf16x8*)&Bs[(wn + nt * 16 + lm) * 64 +
                                              (((ks * 4 + quad) ^ (lm & 7)) * 8)];
#pragma unroll
            for (int mt = 0; mt < 4; mt++)
#pragma unroll
                for (int nt = 0; nt < 4; nt++)
                    acc[mt][nt] = MFMA16(af[mt], bfr[nt], acc[mt][nt], 0, 0, 0);
        }
        __syncthreads();
    }

    float bv4[4];
#pragma unroll
    for (int nt = 0; nt < 4; nt++) bv4[nt] = bias[n0 + wn + nt * 16 + lm];

    if (MODE == 2) {
#pragma unroll
        for (int mt = 0; mt < 4; mt++)
#pragma unroll
            for (int r = 0; r < 4; r++) {
                int rr = wm + mt * 16 + quad * 4 + r;
#pragma unroll
                for (int nt = 0; nt < 4; nt++) {
                    int c = wn + nt * 16 + lm;
                    smem[c * 128 + (rr ^ (8 * (c & 15)))] =
                        (__bf16)((acc[mt][nt][r] + bv4[nt]) * scale);
                }
            }
        __syncthreads();
        const int b = m0 >> 11;
#pragma unroll
        for (int it = 0; it < 8; it++) {
            int g = it * 256 + t;
            int c = g >> 4, gr = g & 15;
            bf16x8 v = *(const bf16x8*)&smem[c * 128 + ((gr * 8) ^ (8 * (c & 15)))];
            int col = n0 + c, hh = col >> 6, dk = col & 63;
            int sglob = (m0 & 2047) + gr * 8;
            size_t idx = (size_t)(b * 16 + hh) * 131072 + (size_t)dk * 2048 + sglob;
            *(bf16x8*)&out[idx] = v;
        }
    } else {
#pragma unroll
        for (int mt = 0; mt < 4; mt++) {
#pragma unroll
            for (int r = 0; r < 4; r++) {
                int row = m0 + wm + mt * 16 + quad * 4 + r;
#pragma unroll
                for (int nt = 0; nt < 4; nt++) {
                    int col = n0 + wn + nt * 16 + lm;
                    float val = (acc[mt][nt][r] + bv4[nt]) * scale;
                    size_t idx;
                    if (MODE == 0) {
                        idx = (size_t)row * 1024 + col;
                    } else {
                        int b = row >> 11, s = row & 2047, hh = col >> 6, dk = col & 63;
                        idx = (size_t)(b * 16 + hh) * 131072 + (size_t)s * 64 + dk;
                    }
                    out[idx] = (OutT)val;
                }
            }
        }
    }
}

__global__ __launch_bounds__(256) void proj_fast3(
        const float* __restrict__ q, const float* __restrict__ k,
        const float* __restrict__ v, const __bf16* __restrict__ WT,
        const float* __restrict__ bq, const float* __restrict__ bk,
        const float* __restrict__ bv,
        __bf16* __restrict__ Q, __bf16* __restrict__ K, __bf16* __restrict__ Vt) {
    int z = blockIdx.z;
    if (z == 0)
        gemm_fast_core<1, true, __bf16>(q, WT, bq, Q, 0.125f);
    else if (z == 1)
        gemm_fast_core<1, true, __bf16>(k, WT + 1048576, bk, K, 1.f);
    else
        gemm_fast_core<2, true, __bf16>(v, WT + 2097152, bv, Vt, 1.f);
}

__global__ __launch_bounds__(256) void out_proj_fast(
        const __bf16* __restrict__ A, const __bf16* __restrict__ Bt,
        const float* __restrict__ bias, float* __restrict__ out) {
    gemm_fast_core<0, false, float>(A, Bt, bias, out, 1.f);
}

// ---------------------------------------------------------------------------
// Flash attention (transposed scores). grid (16,32), block 256 = 4 waves.
// r10 scalar softmax; P-region halved (16 q-rows/wave) with two-pass PV
// -> LDS 49 KB -> 3 blocks/CU.
// ---------------------------------------------------------------------------
__global__ __launch_bounds__(256, 3) void attn_kernel(
        const __bf16* __restrict__ Q, const __bf16* __restrict__ K,
        const __bf16* __restrict__ Vt, __bf16* __restrict__ O) {
    __shared__ __bf16 Ks[8192];
    __shared__ __bf16 Vs[8192];
    __shared__ __bf16 Ps[4 * 16 * 136];
    const int t = threadIdx.x;
    const int wave = t >> 6, lane = t & 63, lm = lane & 15, quad = lane >> 4;
    const int q0 = blockIdx.x * 128;
    const int bh = blockIdx.y;
    const size_t base = (size_t)bh * 131072;

    bf16x8 bq[2][2];
    {
        int qrow = q0 + wave * 32;
#pragma unroll
        for (int nt = 0; nt < 2; nt++)
#pragma unroll
            for (int ks = 0; ks < 2; ks++)
                bq[nt][ks] = *(const bf16x8*)
                    &Q[base + (size_t)(qrow + nt * 16 + lm) * 64 + ks * 32 + quad * 8];
    }

    float m_run[2], l_run[2];
#pragma unroll
    for (int n = 0; n < 2; n++) { m_run[n] = -1e30f; l_run[n] = 0.f; }
    f32x4 o_acc[4][2];
#pragma unroll
    for (int mt = 0; mt < 4; mt++)
#pragma unroll
        for (int n = 0; n < 2; n++) o_acc[mt][n] = zero4();

    __bf16* Pw = &Ps[wave * 16 * 136];

    for (int kv0 = 0; kv0 < 2048; kv0 += 128) {
#pragma unroll
        for (int i = 0; i < 4; i++) {
            int s = i * 256 + t;
            {
                int row = s >> 3, cb = (s & 7) ^ (row & 7);
                load_lds16(&K[base + (size_t)(kv0 + row) * 64 + cb * 8],
                           &Ks[(size_t)(i * 256 + wave * 64) * 8]);
            }
            {
                int row = s >> 4, cb = (s & 15) ^ (row & 15);
                load_lds16(&Vt[base + (size_t)row * 2048 + kv0 + cb * 8],
                           &Vs[(size_t)(i * 256 + wave * 64) * 8]);
            }
        }
        __syncthreads();

        // S^T[kv][q] = K·Q^T (pre-scaled by 1/8 via Q)
        f32x4 sc[8][2];
#pragma unroll
        for (int mt = 0; mt < 8; mt++) {
            sc[mt][0] = zero4();
            sc[mt][1] = zero4();
#pragma unroll
            for (int ks = 0; ks < 2; ks++) {
                bf16x8 ak = *(const bf16x8*)&Ks[(mt * 16 + lm) * 64 +
                                                (((ks * 4 + quad) ^ (lm & 7)) * 8)];
                sc[mt][0] = MFMA16(ak, bq[0][ks], sc[mt][0], 0, 0, 0);
                sc[mt][1] = MFMA16(ak, bq[1][ks], sc[mt][1], 0, 0, 0);
            }
        }

        // per-nt: softmax (r10 scalar form), P write, PV pass
#pragma unroll
        for (int nt = 0; nt < 2; nt++) {
            float mx = -1e30f;
#pragma unroll
            for (int mt = 0; mt < 8; mt++)
#pragma unroll
                for (int r = 0; r < 4; r++) mx = fmaxf(mx, sc[mt][nt][r]);
            mx = fmaxf(mx, __shfl_xor(mx, 16));
            mx = fmaxf(mx, __shfl_xor(mx, 32));
            float mn = fmaxf(m_run[nt], mx);
            float alpha = __expf(m_run[nt] - mn);
            m_run[nt] = mn;
            float su = 0.f;
#pragma unroll
            for (int mt = 0; mt < 8; mt++)
#pragma unroll
                for (int r = 0; r < 4; r++) {
                    float p = __expf(sc[mt][nt][r] - mn);
                    sc[mt][nt][r] = p;
                    su += p;
                }
            su += __shfl_xor(su, 16);
            su += __shfl_xor(su, 32);
            l_run[nt] = l_run[nt] * alpha + su;
#pragma unroll
            for (int mt = 0; mt < 4; mt++)
#pragma unroll
                for (int r = 0; r < 4; r++) o_acc[mt][nt][r] *= alpha;

            // P (this nt's 16 q-rows) -> per-wave LDS, b64-packed
#pragma unroll
            for (int mt = 0; mt < 8; mt++) {
                bf16x4 pk;
#pragma unroll
                for (int r = 0; r < 4; r++) pk[r] = (__bf16)sc[mt][nt][r];
                *(bf16x4*)&Pw[lm * 136 + mt * 16 + quad * 4] = pk;
            }
            __asm__ volatile("" ::: "memory");

            // O^T += Vt·P^T for this nt
#pragma unroll
            for (int ks = 0; ks < 4; ks++) {
                bf16x8 bp = *(const bf16x8*)&Pw[lm * 136 + ks * 32 + quad * 8];
#pragma unroll
                for (int mt = 0; mt < 4; mt++) {
                    bf16x8 av = *(const bf16x8*)&Vs[(mt * 16 + lm) * 128 +
                                                    (((ks * 4 + quad) ^ lm) * 8)];
                    o_acc[mt][nt] = MFMA16(av, bp, o_acc[mt][nt], 0, 0, 0);
                }
            }
            __asm__ volatile("" ::: "memory");
        }
        __syncthreads();
    }

    // epilogue: per-nt divide + transpose via Pw + coalesced b128 stores
    const int b = bh >> 4, h = bh & 15;
#pragma unroll
    for (int nt = 0; nt < 2; nt++) {
        float inv = 1.f / l_run[nt];
#pragma unroll
        for (int mt = 0; mt < 4; mt++) {
            bf16x4 pk;
#pragma unroll
            for (int r = 0; r < 4; r++) pk[r] = (__bf16)(o_acc[mt][nt][r] * inv);
            *(bf16x4*)&Pw[lm * 136 + mt * 16 + quad * 4] = pk;
        }
        __asm__ volatile("" ::: "memory");
        {
            int row = lane >> 2, colb = (lane & 3) * 16;
            int srow = q0 + wave * 32 + nt * 16 + row;
#pragma unroll
            for (int j = 0; j < 2; j++) {
                bf16x8 v = *(const bf16x8*)&Pw[row * 136 + colb + j * 8];
                *(bf16x8*)&O[(size_t)(b * 2048 + srow) * 1024 + h * 64 + colb + j * 8] = v;
            }
        }
        __asm__ volatile("" ::: "memory");
    }
}

// ---------------------------------------------------------------------------
extern "C" void kernel_launch(void* const* d_in, const int* in_sizes, int n_in,
                              void* d_out, int out_size, void* d_ws, size_t ws_size,
                              hipStream_t stream) {
    if (ws_size < ((size_t)40 << 20)) return;

    const float* query = (const float*)d_in[0];
    const float* key_  = (const float*)d_in[1];
    const float* value = (const float*)d_in[2];
    const float* wq = (const float*)d_in[3];
    const float* bq = (const float*)d_in[4];
    const float* wk = (const float*)d_in[5];
    const float* bk = (const float*)d_in[6];
    const float* wv = (const float*)d_in[7];
    const float* bv = (const float*)d_in[8];
    const float* wo = (const float*)d_in[9];
    const float* bo = (const float*)d_in[10];
    float* out = (float*)d_out;

    char* ws = (char*)d_ws;
    __bf16* WT  = (__bf16*)(ws);                       // 8 MB
    __bf16* Qw  = (__bf16*)(ws + ((size_t)8  << 20));
    __bf16* Kw  = (__bf16*)(ws + ((size_t)16 << 20));
    __bf16* Vtw = (__bf16*)(ws + ((size_t)24 << 20));
    __bf16* Ow  = (__bf16*)(ws + ((size_t)32 << 20));

    prep_w<<<dim3(32, 32, 4), dim3(256), 0, stream>>>(wq, wk, wv, wo, WT);
    proj_fast3<<<dim3(8, 32, 3), dim3(256), 0, stream>>>(
        query, key_, value, WT, bq, bk, bv, Qw, Kw, Vtw);
    attn_kernel<<<dim3(16, 32), dim3(256), 0, stream>>>(Qw, Kw, Vtw, Ow);
    out_proj_fast<<<dim3(8, 32), dim3(256), 0, stream>>>(
        Ow, WT + 3 * 1048576, bo, out);
}

// Round 13
// 251.447 us; speedup vs baseline: 1.2251x; 1.2251x over previous
//
#include <hip/hip_runtime.h>

// B=2, S=2048, D=1024, H=16, DK=64. Inputs fp32 dict-order, output fp32.
// Round 13: r10-structure attn (2 blk/CU, no spills) + exp2-domain softmax
// (log2e/8 folded into Q scale); out_proj 128x64 tile (2 blk/CU).

typedef __attribute__((ext_vector_type(8))) __bf16 bf16x8;
typedef __attribute__((ext_vector_type(4))) __bf16 bf16x4;
typedef __attribute__((ext_vector_type(8))) float f32x8;
typedef __attribute__((ext_vector_type(4))) float f32x4;

#define MFMA16 __builtin_amdgcn_mfma_f32_16x16x32_bf16

union Bf8 { bf16x8 v; __bf16 e[8]; };

__device__ inline f32x4 zero4() { f32x4 z; z[0]=z[1]=z[2]=z[3]=0.f; return z; }

__device__ inline float fast_exp2(float x) {
#if __has_builtin(__builtin_amdgcn_exp2f)
    return __builtin_amdgcn_exp2f(x);
#else
    return __expf(x * 0.6931471805599453f);
#endif
}

__device__ inline void load_lds16(const void* g, void* l) {
    __builtin_amdgcn_global_load_lds(
        (const __attribute__((address_space(1))) unsigned int*)g,
        (__attribute__((address_space(3))) unsigned int*)l, 16, 0, 0);
}

// ---------------------------------------------------------------------------
// Weights: transpose + convert. dst[n][k] (bf16) = src[k][n] (fp32).
// ---------------------------------------------------------------------------
__global__ __launch_bounds__(256) void prep_w(
        const float* __restrict__ w0, const float* __restrict__ w1,
        const float* __restrict__ w2, const float* __restrict__ w3,
        __bf16* __restrict__ wt) {
    const int z = blockIdx.z, t = threadIdx.x;
    const float* src = z == 0 ? w0 : z == 1 ? w1 : z == 2 ? w2 : w3;
    __bf16* dst = wt + (size_t)z * 1048576;
    __shared__ float tile[32][33];
    const int tc = t & 31, tr = t >> 5;
    const int r0 = blockIdx.y * 32, c0 = blockIdx.x * 32;
#pragma unroll
    for (int i = 0; i < 4; i++) {
        int r = tr + i * 8;
        tile[r][tc] = src[(size_t)(r0 + r) * 1024 + c0 + tc];
    }
    __syncthreads();
#pragma unroll
    for (int i = 0; i < 4; i++) {
        int r = tr + i * 8;
        dst[(size_t)(c0 + r) * 1024 + r0 + tc] = (__bf16)tile[tc][r];
    }
}

// ---------------------------------------------------------------------------
// FAST GEMM core (128x128, BK=64). B via global_load_lds(16B); A fp32
// vector-load + in-flight convert (AF32) or async bf16, swizzled layout
// (stride 64, block cb at pc = cb ^ (row&7)).
// MODE 0: row-major fp32; 1: Q/K head layout; 2: V^T with LDS-transpose.
// ---------------------------------------------------------------------------
template <int MODE, bool AF32, typename OutT>
__device__ inline void gemm_fast_core(const void* __restrict__ Av,
                                      const __bf16* __restrict__ Bt,
                                      const float* __restrict__ bias,
                                      OutT* __restrict__ out, float scale) {
    __shared__ __bf16 smem[16384];
    __bf16* As = smem;
    __bf16* Bs = smem + 8192;
    const int t = threadIdx.x;
    const int wave = t >> 6, lane = t & 63, lm = lane & 15, quad = lane >> 4;
    const int m0 = blockIdx.y * 128, n0 = blockIdx.x * 128;
    const int wm = (wave >> 1) * 64, wn = (wave & 1) * 64;

    f32x4 acc[4][4];
#pragma unroll
    for (int i = 0; i < 4; i++)
#pragma unroll
        for (int j = 0; j < 4; j++) acc[i][j] = zero4();

    for (int k0 = 0; k0 < 1024; k0 += 64) {
#pragma unroll
        for (int i = 0; i < 4; i++) {
            int s = i * 256 + t;
            int row = s >> 3, cb = (s & 7) ^ (row & 7);
            size_t goff = (size_t)row * 1024 + k0 + cb * 8;
            if (AF32) {
                f32x8 a = *(const f32x8*)&((const float*)Av)[(size_t)m0 * 1024 + goff];
                Bf8 tmp;
#pragma unroll
                for (int j = 0; j < 8; j++) tmp.e[j] = (__bf16)a[j];
                *(bf16x8*)&As[(size_t)s * 8] = tmp.v;
            } else {
                load_lds16(&((const __bf16*)Av)[(size_t)m0 * 1024 + goff],
                           &As[(size_t)(i * 256 + wave * 64) * 8]);
            }
            load_lds16(&Bt[(size_t)n0 * 1024 + goff],
                       &Bs[(size_t)(i * 256 + wave * 64) * 8]);
        }
        __syncthreads();
#pragma unroll
        for (int ks = 0; ks < 2; ks++) {
            bf16x8 af[4], bfr[4];
#pragma unroll
            for (int mt = 0; mt < 4; mt++)
                af[mt] = *(const bf16x8*)&As[(wm + mt * 16 + lm) * 64 +
                                             (((ks * 4 + quad) ^ (lm & 7)) * 8)];
#pragma unroll
            for (int nt = 0; nt < 4; nt++)
                bfr[nt] = *(const bf16x8*)&Bs[(wn + nt * 16 + lm) * 64 +
                                              (((ks * 4 + quad) ^ (lm & 7)) * 8)];
#pragma unroll
            for (int mt = 0; mt < 4; mt++)
#pragma unroll
                for (int nt = 0; nt < 4; nt++)
                    acc[mt][nt] = MFMA16(af[mt], bfr[nt], acc[mt][nt], 0, 0, 0);
        }
        __syncthreads();
    }

    float bv4[4];
#pragma unroll
    for (int nt = 0; nt < 4; nt++) bv4[nt] = bias[n0 + wn + nt * 16 + lm];

    if (MODE == 2) {
#pragma unroll
        for (int mt = 0; mt < 4; mt++)
#pragma unroll
            for (int r = 0; r < 4; r++) {
                int rr = wm + mt * 16 + quad * 4 + r;
#pragma unroll
                for (int nt = 0; nt < 4; nt++) {
                    int c = wn + nt * 16 + lm;
                    smem[c * 128 + (rr ^ (8 * (c & 15)))] =
                        (__bf16)((acc[mt][nt][r] + bv4[nt]) * scale);
                }
            }
        __syncthreads();
        const int b = m0 >> 11;
#pragma unroll
        for (int it = 0; it < 8; it++) {
            int g = it * 256 + t;
            int c = g >> 4, gr = g & 15;
            bf16x8 v = *(const bf16x8*)&smem[c * 128 + ((gr * 8) ^ (8 * (c & 15)))];
            int col = n0 + c, hh = col >> 6, dk = col & 63;
            int sglob = (m0 & 2047) + gr * 8;
            size_t idx = (size_t)(b * 16 + hh) * 131072 + (size_t)dk * 2048 + sglob;
            *(bf16x8*)&out[idx] = v;
        }
    } else {
#pragma unroll
        for (int mt = 0; mt < 4; mt++) {
#pragma unroll
            for (int r = 0; r < 4; r++) {
                int row = m0 + wm + mt * 16 + quad * 4 + r;
#pragma unroll
                for (int nt = 0; nt < 4; nt++) {
                    int col = n0 + wn + nt * 16 + lm;
                    float val = (acc[mt][nt][r] + bv4[nt]) * scale;
                    size_t idx;
                    if (MODE == 0) {
                        idx = (size_t)row * 1024 + col;
                    } else {
                        int b = row >> 11, s = row & 2047, hh = col >> 6, dk = col & 63;
                        idx = (size_t)(b * 16 + hh) * 131072 + (size_t)s * 64 + dk;
                    }
                    out[idx] = (OutT)val;
                }
            }
        }
    }
}

__global__ __launch_bounds__(256) void proj_fast3(
        const float* __restrict__ q, const float* __restrict__ k,
        const float* __restrict__ v, const __bf16* __restrict__ WT,
        const float* __restrict__ bq, const float* __restrict__ bk,
        const float* __restrict__ bv,
        __bf16* __restrict__ Q, __bf16* __restrict__ K, __bf16* __restrict__ Vt) {
    int z = blockIdx.z;
    if (z == 0)  // fold (1/8)*log2(e) so softmax runs in exp2 domain
        gemm_fast_core<1, true, __bf16>(q, WT, bq, Q, 0.18033688f);
    else if (z == 1)
        gemm_fast_core<1, true, __bf16>(k, WT + 1048576, bk, K, 1.f);
    else
        gemm_fast_core<2, true, __bf16>(v, WT + 2097152, bv, Vt, 1.f);
}

// ---------------------------------------------------------------------------
// Out-projection, 128x64 tile (BK=64) -> grid (16,32) = 512 blocks = 2/CU.
// ---------------------------------------------------------------------------
__global__ __launch_bounds__(256) void out_proj_fast64(
        const __bf16* __restrict__ A, const __bf16* __restrict__ Bt,
        const float* __restrict__ bias, float* __restrict__ out) {
    __shared__ __bf16 As[8192];
    __shared__ __bf16 Bs[4096];
    const int t = threadIdx.x;
    const int wave = t >> 6, lane = t & 63, lm = lane & 15, quad = lane >> 4;
    const int m0 = blockIdx.y * 128, n0 = blockIdx.x * 64;
    const int wm = (wave >> 1) * 64, wn = (wave & 1) * 32;

    f32x4 acc[4][2];
#pragma unroll
    for (int i = 0; i < 4; i++) { acc[i][0] = zero4(); acc[i][1] = zero4(); }

    for (int k0 = 0; k0 < 1024; k0 += 64) {
#pragma unroll
        for (int i = 0; i < 4; i++) {
            int s = i * 256 + t;
            int row = s >> 3, cb = (s & 7) ^ (row & 7);
            load_lds16(&A[(size_t)(m0 + row) * 1024 + k0 + cb * 8],
                       &As[(size_t)(i * 256 + wave * 64) * 8]);
            if (i < 2)
                load_lds16(&Bt[(size_t)(n0 + row) * 1024 + k0 + cb * 8],
                           &Bs[(size_t)(i * 256 + wave * 64) * 8]);
        }
        __syncthreads();
#pragma unroll
        for (int ks = 0; ks < 2; ks++) {
            bf16x8 af[4], bfr[2];
#pragma unroll
            for (int mt = 0; mt < 4; mt++)
                af[mt] = *(const bf16x8*)&As[(wm + mt * 16 + lm) * 64 +
                                             (((ks * 4 + quad) ^ (lm & 7)) * 8)];
#pragma unroll
            for (int nt = 0; nt < 2; nt++)
                bfr[nt] = *(const bf16x8*)&Bs[(wn + nt * 16 + lm) * 64 +
                                              (((ks * 4 + quad) ^ (lm & 7)) * 8)];
#pragma unroll
            for (int mt = 0; mt < 4; mt++)
#pragma unroll
                for (int nt = 0; nt < 2; nt++)
                    acc[mt][nt] = MFMA16(af[mt], bfr[nt], acc[mt][nt], 0, 0, 0);
        }
        __syncthreads();
    }

    float bv2[2];
#pragma unroll
    for (int nt = 0; nt < 2; nt++) bv2[nt] = bias[n0 + wn + nt * 16 + lm];

#pragma unroll
    for (int mt = 0; mt < 4; mt++)
#pragma unroll
        for (int r = 0; r < 4; r++) {
            int row = m0 + wm + mt * 16 + quad * 4 + r;
#pragma unroll
            for (int nt = 0; nt < 2; nt++) {
                int col = n0 + wn + nt * 16 + lm;
                out[(size_t)row * 1024 + col] = acc[mt][nt][r] + bv2[nt];
            }
        }
}

// ---------------------------------------------------------------------------
// Flash attention (r10 structure, exp2-domain softmax). grid (16,32),
// block 256 = 4 waves, 2 blocks/CU. Scores arrive scaled by log2e/8 via Q.
// ---------------------------------------------------------------------------
__global__ __launch_bounds__(256, 2) void attn_kernel(
        const __bf16* __restrict__ Q, const __bf16* __restrict__ K,
        const __bf16* __restrict__ Vt, __bf16* __restrict__ O) {
    __shared__ __bf16 Ks[8192];
    __shared__ __bf16 Vs[8192];
    __shared__ __bf16 Ps[4 * 32 * 136];
    const int t = threadIdx.x;
    const int wave = t >> 6, lane = t & 63, lm = lane & 15, quad = lane >> 4;
    const int q0 = blockIdx.x * 128;
    const int bh = blockIdx.y;
    const size_t base = (size_t)bh * 131072;

    bf16x8 bq[2][2];
    {
        int qrow = q0 + wave * 32;
#pragma unroll
        for (int nt = 0; nt < 2; nt++)
#pragma unroll
            for (int ks = 0; ks < 2; ks++)
                bq[nt][ks] = *(const bf16x8*)
                    &Q[base + (size_t)(qrow + nt * 16 + lm) * 64 + ks * 32 + quad * 8];
    }

    float m_run[2], l_run[2];
#pragma unroll
    for (int n = 0; n < 2; n++) { m_run[n] = -1e30f; l_run[n] = 0.f; }
    f32x4 o_acc[4][2];
#pragma unroll
    for (int mt = 0; mt < 4; mt++)
#pragma unroll
        for (int n = 0; n < 2; n++) o_acc[mt][n] = zero4();

    __bf16* Pw = &Ps[wave * 32 * 136];

    for (int kv0 = 0; kv0 < 2048; kv0 += 128) {
#pragma unroll
        for (int i = 0; i < 4; i++) {
            int s = i * 256 + t;
            {
                int row = s >> 3, cb = (s & 7) ^ (row & 7);
                load_lds16(&K[base + (size_t)(kv0 + row) * 64 + cb * 8],
                           &Ks[(size_t)(i * 256 + wave * 64) * 8]);
            }
            {
                int row = s >> 4, cb = (s & 15) ^ (row & 15);
                load_lds16(&Vt[base + (size_t)row * 2048 + kv0 + cb * 8],
                           &Vs[(size_t)(i * 256 + wave * 64) * 8]);
            }
        }
        __syncthreads();

        // S^T[kv][q] = K·Q^T  (already in exp2 domain)
        f32x4 sc[8][2];
#pragma unroll
        for (int mt = 0; mt < 8; mt++) {
            sc[mt][0] = zero4();
            sc[mt][1] = zero4();
#pragma unroll
            for (int ks = 0; ks < 2; ks++) {
                bf16x8 ak = *(const bf16x8*)&Ks[(mt * 16 + lm) * 64 +
                                                (((ks * 4 + quad) ^ (lm & 7)) * 8)];
                sc[mt][0] = MFMA16(ak, bq[0][ks], sc[mt][0], 0, 0, 0);
                sc[mt][1] = MFMA16(ak, bq[1][ks], sc[mt][1], 0, 0, 0);
            }
        }

#pragma unroll
        for (int nt = 0; nt < 2; nt++) {
            float mx = -1e30f;
#pragma unroll
            for (int mt = 0; mt < 8; mt++)
#pragma unroll
                for (int r = 0; r < 4; r++) mx = fmaxf(mx, sc[mt][nt][r]);
            mx = fmaxf(mx, __shfl_xor(mx, 16));
            mx = fmaxf(mx, __shfl_xor(mx, 32));
            float mn = fmaxf(m_run[nt], mx);
            float alpha = fast_exp2(m_run[nt] - mn);
            m_run[nt] = mn;
            float su = 0.f;
#pragma unroll
            for (int mt = 0; mt < 8; mt++)
#pragma unroll
                for (int r = 0; r < 4; r++) {
                    float p = fast_exp2(sc[mt][nt][r] - mn);
                    sc[mt][nt][r] = p;
                    su += p;
                }
            su += __shfl_xor(su, 16);
            su += __shfl_xor(su, 32);
            l_run[nt] = l_run[nt] * alpha + su;
#pragma unroll
            for (int mt = 0; mt < 4; mt++)
#pragma unroll
                for (int r = 0; r < 4; r++) o_acc[mt][nt][r] *= alpha;
        }

        // P -> q-major LDS, b64-packed
#pragma unroll
        for (int nt = 0; nt < 2; nt++)
#pragma unroll
            for (int mt = 0; mt < 8; mt++) {
                bf16x4 pk;
#pragma unroll
                for (int r = 0; r < 4; r++) pk[r] = (__bf16)sc[mt][nt][r];
                *(bf16x4*)&Pw[(nt * 16 + lm) * 136 + mt * 16 + quad * 4] = pk;
            }
        __asm__ volatile("" ::: "memory");

        // O^T += Vt·P^T
#pragma unroll
        for (int ks = 0; ks < 4; ks++) {
            bf16x8 bp[2];
#pragma unroll
            for (int nt = 0; nt < 2; nt++)
                bp[nt] = *(const bf16x8*)&Pw[(nt * 16 + lm) * 136 + ks * 32 + quad * 8];
#pragma unroll
            for (int mt = 0; mt < 4; mt++) {
                bf16x8 av = *(const bf16x8*)&Vs[(mt * 16 + lm) * 128 +
                                                (((ks * 4 + quad) ^ lm) * 8)];
                o_acc[mt][0] = MFMA16(av, bp[0], o_acc[mt][0], 0, 0, 0);
                o_acc[mt][1] = MFMA16(av, bp[1], o_acc[mt][1], 0, 0, 0);
            }
        }
        __syncthreads();
    }

#pragma unroll
    for (int nt = 0; nt < 2; nt++) {
        float inv = 1.f / l_run[nt];
#pragma unroll
        for (int mt = 0; mt < 4; mt++) {
            bf16x4 pk;
#pragma unroll
            for (int r = 0; r < 4; r++) pk[r] = (__bf16)(o_acc[mt][nt][r] * inv);
            *(bf16x4*)&Pw[(nt * 16 + lm) * 136 + mt * 16 + quad * 4] = pk;
        }
    }
    __asm__ volatile("" ::: "memory");
    {
        const int b = bh >> 4, h = bh & 15;
        int ql = lane >> 1, half = lane & 1;
        int srow = q0 + wave * 32 + ql;
#pragma unroll
        for (int j = 0; j < 4; j++) {
            bf16x8 v = *(const bf16x8*)&Pw[ql * 136 + half * 32 + j * 8];
            *(bf16x8*)&O[(size_t)(b * 2048 + srow) * 1024 + h * 64 + half * 32 + j * 8] = v;
        }
    }
}

// ---------------------------------------------------------------------------
extern "C" void kernel_launch(void* const* d_in, const int* in_sizes, int n_in,
                              void* d_out, int out_size, void* d_ws, size_t ws_size,
                              hipStream_t stream) {
    if (ws_size < ((size_t)40 << 20)) return;

    const float* query = (const float*)d_in[0];
    const float* key_  = (const float*)d_in[1];
    const float* value = (const float*)d_in[2];
    const float* wq = (const float*)d_in[3];
    const float* bq = (const float*)d_in[4];
    const float* wk = (const float*)d_in[5];
    const float* bk = (const float*)d_in[6];
    const float* wv = (const float*)d_in[7];
    const float* bv = (const float*)d_in[8];
    const float* wo = (const float*)d_in[9];
    const float* bo = (const float*)d_in[10];
    float* out = (float*)d_out;

    char* ws = (char*)d_ws;
    __bf16* WT  = (__bf16*)(ws);                       // 8 MB
    __bf16* Qw  = (__bf16*)(ws + ((size_t)8  << 20));
    __bf16* Kw  = (__bf16*)(ws + ((size_t)16 << 20));
    __bf16* Vtw = (__bf16*)(ws + ((size_t)24 << 20));
    __bf16* Ow  = (__bf16*)(ws + ((size_t)32 << 20));

    prep_w<<<dim3(32, 32, 4), dim3(256), 0, stream>>>(wq, wk, wv, wo, WT);
    proj_fast3<<<dim3(8, 32, 3), dim3(256), 0, stream>>>(
        query, key_, value, WT, bq, bk, bv, Qw, Kw, Vtw);
    attn_kernel<<<dim3(16, 32), dim3(256), 0, stream>>>(Qw, Kw, Vtw, Ow);
    out_proj_fast64<<<dim3(16, 32), dim3(256), 0, stream>>>(
        Ow, WT + 3 * 1048576, bo, out);
}

// Round 14
// 235.079 us; speedup vs baseline: 1.3104x; 1.0696x over previous
//
#include <hip/hip_runtime.h>

// B=2, S=2048, D=1024, H=16, DK=64. Inputs fp32 dict-order, output fp32.
// Round 14: single 32KB LDS buffer per GEMM block (template instantiations
// were double-allocating -> 64KB, 2 blk/CU); bf16 pre-convert of q/k/v into
// Ow + d_out scratch (lifetimes: Xq dead before attn writes Ow; Xk/Xv dead
// before out_proj writes d_out); proj A staged via async global_load_lds.

typedef __attribute__((ext_vector_type(8))) __bf16 bf16x8;
typedef __attribute__((ext_vector_type(4))) __bf16 bf16x4;
typedef __attribute__((ext_vector_type(8))) float f32x8;
typedef __attribute__((ext_vector_type(4))) float f32x4;

#define MFMA16 __builtin_amdgcn_mfma_f32_16x16x32_bf16

union Bf8 { bf16x8 v; __bf16 e[8]; };

__device__ inline f32x4 zero4() { f32x4 z; z[0]=z[1]=z[2]=z[3]=0.f; return z; }

__device__ inline float fast_exp2(float x) {
#if __has_builtin(__builtin_amdgcn_exp2f)
    return __builtin_amdgcn_exp2f(x);
#else
    return __expf(x * 0.6931471805599453f);
#endif
}

__device__ inline void load_lds16(const void* g, void* l) {
    __builtin_amdgcn_global_load_lds(
        (const __attribute__((address_space(1))) unsigned int*)g,
        (__attribute__((address_space(3))) unsigned int*)l, 16, 0, 0);
}

// ---------------------------------------------------------------------------
// Fused prep. z<4: transpose+convert weight z -> WT[n][k]. z>=4: flat
// fp32->bf16 convert of activation z-4. grid (32,32,7), block 256.
// ---------------------------------------------------------------------------
__global__ __launch_bounds__(256) void prep_all(
        const float* __restrict__ w0, const float* __restrict__ w1,
        const float* __restrict__ w2, const float* __restrict__ w3,
        const float* __restrict__ x0, const float* __restrict__ x1,
        const float* __restrict__ x2,
        __bf16* __restrict__ wt, __bf16* __restrict__ d0,
        __bf16* __restrict__ d1, __bf16* __restrict__ d2) {
    const int z = blockIdx.z, t = threadIdx.x;
    if (z < 4) {
        const float* src = z == 0 ? w0 : z == 1 ? w1 : z == 2 ? w2 : w3;
        __bf16* dst = wt + (size_t)z * 1048576;
        __shared__ float tile[32][33];
        const int tc = t & 31, tr = t >> 5;
        const int r0 = blockIdx.y * 32, c0 = blockIdx.x * 32;
#pragma unroll
        for (int i = 0; i < 4; i++) {
            int r = tr + i * 8;
            tile[r][tc] = src[(size_t)(r0 + r) * 1024 + c0 + tc];
        }
        __syncthreads();
#pragma unroll
        for (int i = 0; i < 4; i++) {
            int r = tr + i * 8;
            dst[(size_t)(c0 + r) * 1024 + r0 + tc] = (__bf16)tile[tc][r];
        }
    } else {
        const float* src = z == 4 ? x0 : z == 5 ? x1 : x2;
        __bf16* dst = z == 4 ? d0 : z == 5 ? d1 : d2;
        int bid = blockIdx.y * 32 + blockIdx.x;
        size_t g = ((size_t)bid * 256 + t) * 16;
#pragma unroll
        for (int h = 0; h < 2; h++) {
            f32x8 a = *(const f32x8*)&src[g + h * 8];
            Bf8 tmp;
#pragma unroll
            for (int j = 0; j < 8; j++) tmp.e[j] = (__bf16)a[j];
            *(bf16x8*)&dst[g + h * 8] = tmp.v;
        }
    }
}

// ---------------------------------------------------------------------------
// FAST GEMM core (128x128, BK=64). Both operands via global_load_lds(16B),
// XOR-swizzled LDS (stride 64, block cb at pc = cb ^ (row&7)). smem (16384
// __bf16 = 32 KB) passed from the kernel so all template instantiations
// share ONE allocation.
// MODE 0: row-major fp32; 1: Q/K head layout; 2: V^T with LDS-transpose.
// ---------------------------------------------------------------------------
template <int MODE, typename OutT>
__device__ inline void gemm_fast_core(__bf16* __restrict__ smem,
                                      const __bf16* __restrict__ A,
                                      const __bf16* __restrict__ Bt,
                                      const float* __restrict__ bias,
                                      OutT* __restrict__ out, float scale) {
    __bf16* As = smem;
    __bf16* Bs = smem + 8192;
    const int t = threadIdx.x;
    const int wave = t >> 6, lane = t & 63, lm = lane & 15, quad = lane >> 4;
    const int m0 = blockIdx.y * 128, n0 = blockIdx.x * 128;
    const int wm = (wave >> 1) * 64, wn = (wave & 1) * 64;

    f32x4 acc[4][4];
#pragma unroll
    for (int i = 0; i < 4; i++)
#pragma unroll
        for (int j = 0; j < 4; j++) acc[i][j] = zero4();

    for (int k0 = 0; k0 < 1024; k0 += 64) {
#pragma unroll
        for (int i = 0; i < 4; i++) {
            int s = i * 256 + t;
            int row = s >> 3, cb = (s & 7) ^ (row & 7);
            size_t goff = (size_t)row * 1024 + k0 + cb * 8;
            load_lds16(&A[(size_t)m0 * 1024 + goff],
                       &As[(size_t)(i * 256 + wave * 64) * 8]);
            load_lds16(&Bt[(size_t)n0 * 1024 + goff],
                       &Bs[(size_t)(i * 256 + wave * 64) * 8]);
        }
        __syncthreads();
#pragma unroll
        for (int ks = 0; ks < 2; ks++) {
            bf16x8 af[4], bfr[4];
#pragma unroll
            for (int mt = 0; mt < 4; mt++)
                af[mt] = *(const bf16x8*)&As[(wm + mt * 16 + lm) * 64 +
                                             (((ks * 4 + quad) ^ (lm & 7)) * 8)];
#pragma unroll
            for (int nt = 0; nt < 4; nt++)
                bfr[nt] = *(const bf16x8*)&Bs[(wn + nt * 16 + lm) * 64 +
                                              (((ks * 4 + quad) ^ (lm & 7)) * 8)];
#pragma unroll
            for (int mt = 0; mt < 4; mt++)
#pragma unroll
                for (int nt = 0; nt < 4; nt++)
                    acc[mt][nt] = MFMA16(af[mt], bfr[nt], acc[mt][nt], 0, 0, 0);
        }
        __syncthreads();
    }

    float bv4[4];
#pragma unroll
    for (int nt = 0; nt < 4; nt++) bv4[nt] = bias[n0 + wn + nt * 16 + lm];

    if (MODE == 2) {
#pragma unroll
        for (int mt = 0; mt < 4; mt++)
#pragma unroll
            for (int r = 0; r < 4; r++) {
                int rr = wm + mt * 16 + quad * 4 + r;
#pragma unroll
                for (int nt = 0; nt < 4; nt++) {
                    int c = wn + nt * 16 + lm;
                    smem[c * 128 + (rr ^ (8 * (c & 15)))] =
                        (__bf16)((acc[mt][nt][r] + bv4[nt]) * scale);
                }
            }
        __syncthreads();
        const int b = m0 >> 11;
#pragma unroll
        for (int it = 0; it < 8; it++) {
            int g = it * 256 + t;
            int c = g >> 4, gr = g & 15;
            bf16x8 v = *(const bf16x8*)&smem[c * 128 + ((gr * 8) ^ (8 * (c & 15)))];
            int col = n0 + c, hh = col >> 6, dk = col & 63;
            int sglob = (m0 & 2047) + gr * 8;
            size_t idx = (size_t)(b * 16 + hh) * 131072 + (size_t)dk * 2048 + sglob;
            *(bf16x8*)&out[idx] = v;
        }
    } else {
#pragma unroll
        for (int mt = 0; mt < 4; mt++) {
#pragma unroll
            for (int r = 0; r < 4; r++) {
                int row = m0 + wm + mt * 16 + quad * 4 + r;
#pragma unroll
                for (int nt = 0; nt < 4; nt++) {
                    int col = n0 + wn + nt * 16 + lm;
                    float val = (acc[mt][nt][r] + bv4[nt]) * scale;
                    size_t idx;
                    if (MODE == 0) {
                        idx = (size_t)row * 1024 + col;
                    } else {
                        int b = row >> 11, s = row & 2047, hh = col >> 6, dk = col & 63;
                        idx = (size_t)(b * 16 + hh) * 131072 + (size_t)s * 64 + dk;
                    }
                    out[idx] = (OutT)val;
                }
            }
        }
    }
}

__global__ __launch_bounds__(256) void proj_fast3(
        const __bf16* __restrict__ xq, const __bf16* __restrict__ xk,
        const __bf16* __restrict__ xv, const __bf16* __restrict__ WT,
        const float* __restrict__ bq, const float* __restrict__ bk,
        const float* __restrict__ bv,
        __bf16* __restrict__ Q, __bf16* __restrict__ K, __bf16* __restrict__ Vt) {
    __shared__ __bf16 smem[16384];
    int z = blockIdx.z;
    if (z == 0)  // fold (1/8)*log2(e): softmax runs in exp2 domain
        gemm_fast_core<1, __bf16>(smem, xq, WT, bq, Q, 0.18033688f);
    else if (z == 1)
        gemm_fast_core<1, __bf16>(smem, xk, WT + 1048576, bk, K, 1.f);
    else
        gemm_fast_core<2, __bf16>(smem, xv, WT + 2097152, bv, Vt, 1.f);
}

// ---------------------------------------------------------------------------
// Out-projection, 128x64 tile (BK=64) -> grid (16,32) = 512 blocks.
// ---------------------------------------------------------------------------
__global__ __launch_bounds__(256) void out_proj_fast64(
        const __bf16* __restrict__ A, const __bf16* __restrict__ Bt,
        const float* __restrict__ bias, float* __restrict__ out) {
    __shared__ __bf16 As[8192];
    __shared__ __bf16 Bs[4096];
    const int t = threadIdx.x;
    const int wave = t >> 6, lane = t & 63, lm = lane & 15, quad = lane >> 4;
    const int m0 = blockIdx.y * 128, n0 = blockIdx.x * 64;
    const int wm = (wave >> 1) * 64, wn = (wave & 1) * 32;

    f32x4 acc[4][2];
#pragma unroll
    for (int i = 0; i < 4; i++) { acc[i][0] = zero4(); acc[i][1] = zero4(); }

    for (int k0 = 0; k0 < 1024; k0 += 64) {
#pragma unroll
        for (int i = 0; i < 4; i++) {
            int s = i * 256 + t;
            int row = s >> 3, cb = (s & 7) ^ (row & 7);
            load_lds16(&A[(size_t)(m0 + row) * 1024 + k0 + cb * 8],
                       &As[(size_t)(i * 256 + wave * 64) * 8]);
            if (i < 2)
                load_lds16(&Bt[(size_t)(n0 + row) * 1024 + k0 + cb * 8],
                           &Bs[(size_t)(i * 256 + wave * 64) * 8]);
        }
        __syncthreads();
#pragma unroll
        for (int ks = 0; ks < 2; ks++) {
            bf16x8 af[4], bfr[2];
#pragma unroll
            for (int mt = 0; mt < 4; mt++)
                af[mt] = *(const bf16x8*)&As[(wm + mt * 16 + lm) * 64 +
                                             (((ks * 4 + quad) ^ (lm & 7)) * 8)];
#pragma unroll
            for (int nt = 0; nt < 2; nt++)
                bfr[nt] = *(const bf16x8*)&Bs[(wn + nt * 16 + lm) * 64 +
                                              (((ks * 4 + quad) ^ (lm & 7)) * 8)];
#pragma unroll
            for (int mt = 0; mt < 4; mt++)
#pragma unroll
                for (int nt = 0; nt < 2; nt++)
                    acc[mt][nt] = MFMA16(af[mt], bfr[nt], acc[mt][nt], 0, 0, 0);
        }
        __syncthreads();
    }

    float bv2[2];
#pragma unroll
    for (int nt = 0; nt < 2; nt++) bv2[nt] = bias[n0 + wn + nt * 16 + lm];

#pragma unroll
    for (int mt = 0; mt < 4; mt++)
#pragma unroll
        for (int r = 0; r < 4; r++) {
            int row = m0 + wm + mt * 16 + quad * 4 + r;
#pragma unroll
            for (int nt = 0; nt < 2; nt++) {
                int col = n0 + wn + nt * 16 + lm;
                out[(size_t)row * 1024 + col] = acc[mt][nt][r] + bv2[nt];
            }
        }
}

// ---------------------------------------------------------------------------
// Flash attention (r13 structure, exp2-domain softmax). grid (16,32),
// block 256 = 4 waves, 2 blocks/CU.
// ---------------------------------------------------------------------------
__global__ __launch_bounds__(256, 2) void attn_kernel(
        const __bf16* __restrict__ Q, const __bf16* __restrict__ K,
        const __bf16* __restrict__ Vt, __bf16* __restrict__ O) {
    __shared__ __bf16 Ks[8192];
    __shared__ __bf16 Vs[8192];
    __shared__ __bf16 Ps[4 * 32 * 136];
    const int t = threadIdx.x;
    const int wave = t >> 6, lane = t & 63, lm = lane & 15, quad = lane >> 4;
    const int q0 = blockIdx.x * 128;
    const int bh = blockIdx.y;
    const size_t base = (size_t)bh * 131072;

    bf16x8 bq[2][2];
    {
        int qrow = q0 + wave * 32;
#pragma unroll
        for (int nt = 0; nt < 2; nt++)
#pragma unroll
            for (int ks = 0; ks < 2; ks++)
                bq[nt][ks] = *(const bf16x8*)
                    &Q[base + (size_t)(qrow + nt * 16 + lm) * 64 + ks * 32 + quad * 8];
    }

    float m_run[2], l_run[2];
#pragma unroll
    for (int n = 0; n < 2; n++) { m_run[n] = -1e30f; l_run[n] = 0.f; }
    f32x4 o_acc[4][2];
#pragma unroll
    for (int mt = 0; mt < 4; mt++)
#pragma unroll
        for (int n = 0; n < 2; n++) o_acc[mt][n] = zero4();

    __bf16* Pw = &Ps[wave * 32 * 136];

    for (int kv0 = 0; kv0 < 2048; kv0 += 128) {
#pragma unroll
        for (int i = 0; i < 4; i++) {
            int s = i * 256 + t;
            {
                int row = s >> 3, cb = (s & 7) ^ (row & 7);
                load_lds16(&K[base + (size_t)(kv0 + row) * 64 + cb * 8],
                           &Ks[(size_t)(i * 256 + wave * 64) * 8]);
            }
            {
                int row = s >> 4, cb = (s & 15) ^ (row & 15);
                load_lds16(&Vt[base + (size_t)row * 2048 + kv0 + cb * 8],
                           &Vs[(size_t)(i * 256 + wave * 64) * 8]);
            }
        }
        __syncthreads();

        f32x4 sc[8][2];
#pragma unroll
        for (int mt = 0; mt < 8; mt++) {
            sc[mt][0] = zero4();
            sc[mt][1] = zero4();
#pragma unroll
            for (int ks = 0; ks < 2; ks++) {
                bf16x8 ak = *(const bf16x8*)&Ks[(mt * 16 + lm) * 64 +
                                                (((ks * 4 + quad) ^ (lm & 7)) * 8)];
                sc[mt][0] = MFMA16(ak, bq[0][ks], sc[mt][0], 0, 0, 0);
                sc[mt][1] = MFMA16(ak, bq[1][ks], sc[mt][1], 0, 0, 0);
            }
        }

#pragma unroll
        for (int nt = 0; nt < 2; nt++) {
            float mx = -1e30f;
#pragma unroll
            for (int mt = 0; mt < 8; mt++)
#pragma unroll
                for (int r = 0; r < 4; r++) mx = fmaxf(mx, sc[mt][nt][r]);
            mx = fmaxf(mx, __shfl_xor(mx, 16));
            mx = fmaxf(mx, __shfl_xor(mx, 32));
            float mn = fmaxf(m_run[nt], mx);
            float alpha = fast_exp2(m_run[nt] - mn);
            m_run[nt] = mn;
            float su = 0.f;
#pragma unroll
            for (int mt = 0; mt < 8; mt++)
#pragma unroll
                for (int r = 0; r < 4; r++) {
                    float p = fast_exp2(sc[mt][nt][r] - mn);
                    sc[mt][nt][r] = p;
                    su += p;
                }
            su += __shfl_xor(su, 16);
            su += __shfl_xor(su, 32);
            l_run[nt] = l_run[nt] * alpha + su;
#pragma unroll
            for (int mt = 0; mt < 4; mt++)
#pragma unroll
                for (int r = 0; r < 4; r++) o_acc[mt][nt][r] *= alpha;
        }

#pragma unroll
        for (int nt = 0; nt < 2; nt++)
#pragma unroll
            for (int mt = 0; mt < 8; mt++) {
                bf16x4 pk;
#pragma unroll
                for (int r = 0; r < 4; r++) pk[r] = (__bf16)sc[mt][nt][r];
                *(bf16x4*)&Pw[(nt * 16 + lm) * 136 + mt * 16 + quad * 4] = pk;
            }
        __asm__ volatile("" ::: "memory");

#pragma unroll
        for (int ks = 0; ks < 4; ks++) {
            bf16x8 bp[2];
#pragma unroll
            for (int nt = 0; nt < 2; nt++)
                bp[nt] = *(const bf16x8*)&Pw[(nt * 16 + lm) * 136 + ks * 32 + quad * 8];
#pragma unroll
            for (int mt = 0; mt < 4; mt++) {
                bf16x8 av = *(const bf16x8*)&Vs[(mt * 16 + lm) * 128 +
                                                (((ks * 4 + quad) ^ lm) * 8)];
                o_acc[mt][0] = MFMA16(av, bp[0], o_acc[mt][0], 0, 0, 0);
                o_acc[mt][1] = MFMA16(av, bp[1], o_acc[mt][1], 0, 0, 0);
            }
        }
        __syncthreads();
    }

#pragma unroll
    for (int nt = 0; nt < 2; nt++) {
        float inv = 1.f / l_run[nt];
#pragma unroll
        for (int mt = 0; mt < 4; mt++) {
            bf16x4 pk;
#pragma unroll
            for (int r = 0; r < 4; r++) pk[r] = (__bf16)(o_acc[mt][nt][r] * inv);
            *(bf16x4*)&Pw[(nt * 16 + lm) * 136 + mt * 16 + quad * 4] = pk;
        }
    }
    __asm__ volatile("" ::: "memory");
    {
        const int b = bh >> 4, h = bh & 15;
        int ql = lane >> 1, half = lane & 1;
        int srow = q0 + wave * 32 + ql;
#pragma unroll
        for (int j = 0; j < 4; j++) {
            bf16x8 v = *(const bf16x8*)&Pw[ql * 136 + half * 32 + j * 8];
            *(bf16x8*)&O[(size_t)(b * 2048 + srow) * 1024 + h * 64 + half * 32 + j * 8] = v;
        }
    }
}

// ---------------------------------------------------------------------------
extern "C" void kernel_launch(void* const* d_in, const int* in_sizes, int n_in,
                              void* d_out, int out_size, void* d_ws, size_t ws_size,
                              hipStream_t stream) {
    if (ws_size < ((size_t)40 << 20)) return;

    const float* query = (const float*)d_in[0];
    const float* key_  = (const float*)d_in[1];
    const float* value = (const float*)d_in[2];
    const float* wq = (const float*)d_in[3];
    const float* bq = (const float*)d_in[4];
    const float* wk = (const float*)d_in[5];
    const float* bk = (const float*)d_in[6];
    const float* wv = (const float*)d_in[7];
    const float* bv = (const float*)d_in[8];
    const float* wo = (const float*)d_in[9];
    const float* bo = (const float*)d_in[10];
    float* out = (float*)d_out;

    char* ws = (char*)d_ws;
    __bf16* WT  = (__bf16*)(ws);                       // 8 MB
    __bf16* Qw  = (__bf16*)(ws + ((size_t)8  << 20));
    __bf16* Kw  = (__bf16*)(ws + ((size_t)16 << 20));
    __bf16* Vtw = (__bf16*)(ws + ((size_t)24 << 20));
    __bf16* Ow  = (__bf16*)(ws + ((size_t)32 << 20));  // 8 MB

    // bf16 activation scratch: Xq aliases Ow (dead until attn writes it);
    // Xk/Xv live in d_out (16.8 MB fp32; dead until out_proj writes it).
    __bf16* Xq = Ow;
    __bf16* Xk = (__bf16*)d_out;
    __bf16* Xv = (__bf16*)d_out + 4194304;

    prep_all<<<dim3(32, 32, 7), dim3(256), 0, stream>>>(
        wq, wk, wv, wo, query, key_, value, WT, Xq, Xk, Xv);
    proj_fast3<<<dim3(8, 32, 3), dim3(256), 0, stream>>>(
        Xq, Xk, Xv, WT, bq, bk, bv, Qw, Kw, Vtw);
    attn_kernel<<<dim3(16, 32), dim3(256), 0, stream>>>(Qw, Kw, Vtw, Ow);
    out_proj_fast64<<<dim3(16, 32), dim3(256), 0, stream>>>(
        Ow, WT + 3 * 1048576, bo, out);
}